// Round 12
// baseline (783.015 us; speedup 1.0000x reference)
//
#include <hip/hip_runtime.h>
#include <hip/hip_bf16.h>

#define HH 1024
#define FF 4096
#define MTOT (8 * 2048)

typedef __attribute__((ext_vector_type(4))) float f32x4;
typedef __attribute__((ext_vector_type(4))) int   i32x4;
typedef __attribute__((ext_vector_type(8))) short bf16x8;

__device__ inline void async_load16(const void* g, void* l) {
    __builtin_amdgcn_global_load_lds(
        (const __attribute__((address_space(1))) unsigned int*)g,
        (__attribute__((address_space(3))) unsigned int*)l, 16, 0, 0);
}
__device__ inline unsigned lds_off(void* p) {
    return (unsigned)(size_t)(__attribute__((address_space(3))) char*)p;
}
template<int OFF>
__device__ inline i32x4 dsr(unsigned addr) {
    i32x4 r;
    asm volatile("ds_read_b128 %0, %1 offset:%2" : "=v"(r) : "v"(addr), "n"(OFF));
    return r;
}
#define SBAR()  __builtin_amdgcn_s_barrier()
#define LGKM0() do { asm volatile("s_waitcnt lgkmcnt(0)"); \
                     __builtin_amdgcn_sched_barrier(0); } while (0)
#define WAIT_VM0() asm volatile("s_waitcnt vmcnt(0)")

__device__ inline float b2f(short s) {
    unsigned u = ((unsigned)(unsigned short)s) << 16;
    float f; __builtin_memcpy(&f, &u, 4); return f;
}
__device__ inline int q8(float f) {
    int v = __float2int_rn(f);
    return v < -127 ? -127 : (v > 127 ? 127 : v);
}

// frag loads: base VGPR + compile-time offset. Row stride 128 B (identical to R11).
template<int B0, int MH>
__device__ inline void ldA8(i32x4 (&d)[4][2], unsigned v0, unsigned v1) {
    constexpr int B = B0 + MH * 8192;
    d[0][0] = dsr<B + 0>(v0);     d[0][1] = dsr<B + 0>(v1);
    d[1][0] = dsr<B + 2048>(v0);  d[1][1] = dsr<B + 2048>(v1);
    d[2][0] = dsr<B + 4096>(v0);  d[2][1] = dsr<B + 4096>(v1);
    d[3][0] = dsr<B + 6144>(v0);  d[3][1] = dsr<B + 6144>(v1);
}
template<int B0>
__device__ inline void ldB8(i32x4 (&d)[4][2], unsigned v0, unsigned v1) {
    d[0][0] = dsr<B0 + 0>(v0);     d[0][1] = dsr<B0 + 0>(v1);
    d[1][0] = dsr<B0 + 2048>(v0);  d[1][1] = dsr<B0 + 2048>(v1);
    d[2][0] = dsr<B0 + 4096>(v0);  d[2][1] = dsr<B0 + 4096>(v1);
    d[3][0] = dsr<B0 + 6144>(v0);  d[3][1] = dsr<B0 + 6144>(v1);
}

// ---------------- repack: q[K][N] int32 (zp=128) -> wq[N][K] int8
__global__ void repack_kernel(const int* __restrict__ q, char* __restrict__ wq,
                              int K, int N)
{
    __shared__ char tile[32][33];
    const int n0 = blockIdx.x * 32, k0 = blockIdx.y * 32;
    const int tx = threadIdx.x, ty = threadIdx.y; // (32,8)
#pragma unroll
    for (int i = 0; i < 32; i += 8)
        tile[ty + i][tx] = (char)(q[(size_t)(k0 + ty + i) * N + n0 + tx] - 128);
    __syncthreads();
#pragma unroll
    for (int i = 0; i < 32; i += 8)
        wq[(size_t)(n0 + ty + i) * K + k0 + tx] = tile[tx][ty + i];
}

// ---------------- LayerNorm + per-row int8 quant
__global__ __launch_bounds__(256)
void ln_q_kernel(const float* __restrict__ x, const float* __restrict__ gamma,
                 const float* __restrict__ beta, char* __restrict__ hq,
                 float* __restrict__ hs, int m0)
{
    const int row = m0 + blockIdx.x;
    const float4 v = ((const float4*)(x + (size_t)row * HH))[threadIdx.x];
    float s  = v.x + v.y + v.z + v.w;
    float ss = v.x * v.x + v.y * v.y + v.z * v.z + v.w * v.w;
#pragma unroll
    for (int o = 32; o > 0; o >>= 1) { s += __shfl_down(s, o); ss += __shfl_down(ss, o); }
    __shared__ float red[8];
    const int wid = threadIdx.x >> 6, lane = threadIdx.x & 63;
    if (lane == 0) { red[wid] = s; red[4 + wid] = ss; }
    __syncthreads();
    if (threadIdx.x == 0) {
        red[0] = red[0] + red[1] + red[2] + red[3];
        red[4] = red[4] + red[5] + red[6] + red[7];
    }
    __syncthreads();
    const float mu   = red[0] * (1.f / HH);
    const float rstd = rsqrtf(red[4] * (1.f / HH) - mu * mu + 1e-5f);
    const float4 g = ((const float4*)gamma)[threadIdx.x];
    const float4 b = ((const float4*)beta)[threadIdx.x];
    float h0 = (v.x - mu) * rstd * g.x + b.x;
    float h1 = (v.y - mu) * rstd * g.y + b.y;
    float h2 = (v.z - mu) * rstd * g.z + b.z;
    float h3 = (v.w - mu) * rstd * g.w + b.w;
    float mx = fmaxf(fmaxf(fabsf(h0), fabsf(h1)), fmaxf(fabsf(h2), fabsf(h3)));
#pragma unroll
    for (int o = 32; o > 0; o >>= 1) mx = fmaxf(mx, __shfl_down(mx, o));
    __syncthreads();
    if (lane == 0) red[wid] = mx;
    __syncthreads();
    if (threadIdx.x == 0)
        red[0] = fmaxf(fmaxf(red[0], red[1]), fmaxf(red[2], red[3]));
    __syncthreads();
    const float m = fmaxf(red[0], 1e-12f);
    const float inv = 127.f / m;
    const int q0 = q8(h0 * inv), q1 = q8(h1 * inv), q2 = q8(h2 * inv), q3 = q8(h3 * inv);
    ((int*)(hq + (size_t)blockIdx.x * HH))[threadIdx.x] =
        (q0 & 255) | ((q1 & 255) << 8) | ((q2 & 255) << 16) | ((q3 & 255) << 24);
    if (threadIdx.x == 0) hs[blockIdx.x] = m / 127.f;
}

// ---------------- GEMM1: yq = quant( silu(hs*(hq@w1q scaled) + b1) ), + ys per (g,row)
__global__ __launch_bounds__(512, 2)
void gemm1_i8(const char* __restrict__ A, const char* __restrict__ Bt,
              const float* __restrict__ s1, const float* __restrict__ hs,
              const float* __restrict__ bias,
              char* __restrict__ yq, float* __restrict__ ys,
              int Mrows, int nbx)
{
    constexpr int KK = HH;          // bytes per row
    constexpr int NT = KK / 128;    // 8
    __shared__ __align__(16) char SMc[131072];

    const int nwg = (int)gridDim.x, bq = (int)blockIdx.x;
    const int q = nwg >> 3, r = nwg & 7;
    const int xcd = bq & 7, pos = bq >> 3;
    const int bid = (xcd < r) ? xcd * (q + 1) + pos
                              : r * (q + 1) + (xcd - r) * q + pos;
    const int bx = bid % nbx, by = bid / nbx;
    const int rowA0 = by * 256, colB0 = bx * 256;

    const int tid = (int)threadIdx.x;
    const int lane = tid & 63, wid = tid >> 6;
    const int wr = wid >> 2, wc = wid & 3;
    const int lrow = lane & 15, kg = lane >> 4;
    const int swz = lrow & 7;

    const int srow = tid >> 3;
    const int sgs  = (tid & 7) ^ (srow & 7);
    const char* aSrc = A  + (size_t)(rowA0 + srow) * KK + sgs * 16;
    const char* bSrc = Bt + (size_t)(colB0 + srow) * KK + sgs * 16;
    char* aDst = SMc + srow * 128 + (tid & 7) * 16;
    char* bDst = SMc + 65536 + srow * 128 + (tid & 7) * 16;

    const unsigned asB = lds_off(SMc);
    const unsigned k0off = (unsigned)((kg ^ swz) << 4);
    const unsigned k1off = (unsigned)(((4 + kg) ^ swz) << 4);
    const unsigned vA0 = asB + (unsigned)((wr * 128 + lrow) * 128) + k0off;
    const unsigned vA1 = asB + (unsigned)((wr * 128 + lrow) * 128) + k1off;
    const unsigned vB0 = asB + 65536u + (unsigned)((wc * 64 + lrow) * 128) + k0off;
    const unsigned vB1 = asB + 65536u + (unsigned)((wc * 64 + lrow) * 128) + k1off;

    auto stA = [&](int buf, int t) {
        const char* s0 = aSrc + t * 128;
        char* d = aDst + buf * 32768;
        async_load16(s0, d);
        async_load16(s0 + (size_t)64 * KK,  d + 8192);
        async_load16(s0 + (size_t)128 * KK, d + 16384);
        async_load16(s0 + (size_t)192 * KK, d + 24576);
    };
    auto stB = [&](int buf, int t) {
        const char* s0 = bSrc + t * 128;
        char* d = bDst + buf * 32768;
        async_load16(s0, d);
        async_load16(s0 + (size_t)64 * KK,  d + 8192);
        async_load16(s0 + (size_t)128 * KK, d + 16384);
        async_load16(s0 + (size_t)192 * KK, d + 24576);
    };

    f32x4 acc[8][4] = {};
    const i32x4 zero = {0, 0, 0, 0};
    i32x4 a[4][2], b[4][2];
    float sc[4];

    auto half = [&](int mh) {
        __builtin_amdgcn_s_setprio(1);
#pragma unroll
        for (int mi = 0; mi < 4; ++mi)
#pragma unroll
            for (int ni = 0; ni < 4; ++ni) {
                i32x4 t = __builtin_amdgcn_mfma_i32_16x16x64_i8(a[mi][0], b[ni][0], zero, 0, 0, 0);
                t = __builtin_amdgcn_mfma_i32_16x16x64_i8(a[mi][1], b[ni][1], t, 0, 0, 0);
                f32x4& A_ = acc[mh * 4 + mi][ni];
                A_[0] += sc[ni] * (float)t[0];
                A_[1] += sc[ni] * (float)t[1];
                A_[2] += sc[ni] * (float)t[2];
                A_[3] += sc[ni] * (float)t[3];
            }
        __builtin_amdgcn_s_setprio(0);
    };

    // prologue
    stA(0, 0); stB(0, 0);
    WAIT_VM0();
    SBAR();

    const int NI = NT >> 1;
    for (int i = 0; i < NI; ++i) {
        const int c = 2 * i, n = 2 * i + 1;
        // T1: compute buf0 (group c); stage buf1 <- group n
#pragma unroll
        for (int ni = 0; ni < 4; ++ni)
            sc[ni] = s1[(size_t)c * FF + colB0 + wc * 64 + ni * 16 + lrow];
        stA(1, n); stB(1, n);
        ldB8<0>(b, vB0, vB1);
        ldA8<0, 0>(a, vA0, vA1);
        LGKM0();
        half(0);
        ldA8<0, 1>(a, vA0, vA1);
        LGKM0();
        half(1);
        WAIT_VM0();
        SBAR();
        // T2: compute buf1 (group n); stage buf0 <- group c+2
#pragma unroll
        for (int ni = 0; ni < 4; ++ni)
            sc[ni] = s1[(size_t)n * FF + colB0 + wc * 64 + ni * 16 + lrow];
        if (i < NI - 1) { stA(0, c + 2); stB(0, c + 2); }
        ldB8<32768>(b, vB0, vB1);
        ldA8<32768, 0>(a, vA0, vA1);
        LGKM0();
        half(0);
        ldA8<32768, 1>(a, vA0, vA1);
        LGKM0();
        half(1);
        WAIT_VM0();
        SBAR();
    }

    // ---- epilogue: y = silu(hs*acc + b1) -> LDS (bf16, swizzled) -> quant yq + ys
    __syncthreads();
    short* smh = (short*)SMc;
    f32x4 hv[8];
#pragma unroll
    for (int mi = 0; mi < 8; ++mi)
        hv[mi] = *(const f32x4*)(hs + rowA0 + wr * 128 + mi * 16 + kg * 4);
#pragma unroll
    for (int ni = 0; ni < 4; ++ni) {
        const int col = wc * 64 + ni * 16 + lrow;
        const float bv = bias[colB0 + col];
#pragma unroll
        for (int mi = 0; mi < 8; ++mi) {
#pragma unroll
            for (int j = 0; j < 4; ++j) {
                const int rowl = wr * 128 + mi * 16 + kg * 4 + j;
                const float v = hv[mi][j] * acc[mi][ni][j] + bv;
                const float sv = v / (1.f + __expf(-v));
                const __hip_bfloat16 hb = __float2bfloat16(sv);
                smh[rowl * 256 + ((((col >> 3) ^ (rowl & 7)) << 3) | (col & 7))] =
                    *(const short*)&hb;
            }
        }
    }
    __syncthreads();
    {
        const int rowl = tid >> 1, hf2 = tid & 1;
        const int r7 = rowl & 7;
        short* rp = smh + rowl * 256;
        float mx = 0.f;
#pragma unroll
        for (int u = 0; u < 16; ++u) {
            const int sslot = hf2 * 16 + u;
            const bf16x8 vv = *(const bf16x8*)(rp + ((sslot ^ r7) << 3));
#pragma unroll
            for (int e = 0; e < 8; ++e) mx = fmaxf(mx, fabsf(b2f(vv[e])));
        }
        const float mc = fmaxf(mx, 1e-12f);
        const float ysv = mc / 127.f, inv = 127.f / mc;
        ys[(size_t)(bx * 2 + hf2) * Mrows + rowA0 + rowl] = ysv;
        char* yrow = yq + (size_t)(rowA0 + rowl) * FF + colB0 + hf2 * 128;
#pragma unroll
        for (int u2 = 0; u2 < 8; ++u2) {
            const int s0 = hf2 * 16 + u2 * 2, s1_ = s0 + 1;
            const bf16x8 v0 = *(const bf16x8*)(rp + ((s0 ^ r7) << 3));
            const bf16x8 v1 = *(const bf16x8*)(rp + ((s1_ ^ r7) << 3));
            int w[4];
#pragma unroll
            for (int k = 0; k < 2; ++k) {
                const bf16x8& vv = k ? v1 : v0;
#pragma unroll
                for (int hq4 = 0; hq4 < 2; ++hq4) {
                    const int e0 = hq4 * 4;
                    const int a0 = q8(b2f(vv[e0 + 0]) * inv), a1 = q8(b2f(vv[e0 + 1]) * inv);
                    const int a2 = q8(b2f(vv[e0 + 2]) * inv), a3 = q8(b2f(vv[e0 + 3]) * inv);
                    w[k * 2 + hq4] = (a0 & 255) | ((a1 & 255) << 8) |
                                     ((a2 & 255) << 16) | ((a3 & 255) << 24);
                }
            }
            *(i32x4*)(yrow + u2 * 16) = (i32x4){w[0], w[1], w[2], w[3]};
        }
    }
}

// ---------------- GEMM2: out = resid + 0.5*( (yq@w2q) scaled(ys,s2) + b2 )
__global__ __launch_bounds__(512, 2)
void gemm2_i8(const char* __restrict__ A, const char* __restrict__ Bt,
              const float* __restrict__ s2, const float* __restrict__ ys,
              const float* __restrict__ bias, const float* __restrict__ resid,
              float* __restrict__ out, int Mrows, int nbx)
{
    constexpr int KK = FF;          // 4096 bytes per row
    constexpr int NT = KK / 128;    // 32
    __shared__ __align__(16) char SMc[131072];

    const int nwg = (int)gridDim.x, bq = (int)blockIdx.x;
    const int q = nwg >> 3, r = nwg & 7;
    const int xcd = bq & 7, pos = bq >> 3;
    const int bid = (xcd < r) ? xcd * (q + 1) + pos
                              : r * (q + 1) + (xcd - r) * q + pos;
    const int bx = bid % nbx, by = bid / nbx;
    const int rowA0 = by * 256, colB0 = bx * 256;

    const int tid = (int)threadIdx.x;
    const int lane = tid & 63, wid = tid >> 6;
    const int wr = wid >> 2, wc = wid & 3;
    const int lrow = lane & 15, kg = lane >> 4;
    const int swz = lrow & 7;

    const int srow = tid >> 3;
    const int sgs  = (tid & 7) ^ (srow & 7);
    const char* aSrc = A  + (size_t)(rowA0 + srow) * KK + sgs * 16;
    const char* bSrc = Bt + (size_t)(colB0 + srow) * KK + sgs * 16;
    char* aDst = SMc + srow * 128 + (tid & 7) * 16;
    char* bDst = SMc + 65536 + srow * 128 + (tid & 7) * 16;

    const unsigned asB = lds_off(SMc);
    const unsigned k0off = (unsigned)((kg ^ swz) << 4);
    const unsigned k1off = (unsigned)(((4 + kg) ^ swz) << 4);
    const unsigned vA0 = asB + (unsigned)((wr * 128 + lrow) * 128) + k0off;
    const unsigned vA1 = asB + (unsigned)((wr * 128 + lrow) * 128) + k1off;
    const unsigned vB0 = asB + 65536u + (unsigned)((wc * 64 + lrow) * 128) + k0off;
    const unsigned vB1 = asB + 65536u + (unsigned)((wc * 64 + lrow) * 128) + k1off;

    auto stA = [&](int buf, int t) {
        const char* s0 = aSrc + t * 128;
        char* d = aDst + buf * 32768;
        async_load16(s0, d);
        async_load16(s0 + (size_t)64 * KK,  d + 8192);
        async_load16(s0 + (size_t)128 * KK, d + 16384);
        async_load16(s0 + (size_t)192 * KK, d + 24576);
    };
    auto stB = [&](int buf, int t) {
        const char* s0 = bSrc + t * 128;
        char* d = bDst + buf * 32768;
        async_load16(s0, d);
        async_load16(s0 + (size_t)64 * KK,  d + 8192);
        async_load16(s0 + (size_t)128 * KK, d + 16384);
        async_load16(s0 + (size_t)192 * KK, d + 24576);
    };

    f32x4 acc[8][4] = {};
    const i32x4 zero = {0, 0, 0, 0};
    i32x4 a[4][2], b[4][2];
    f32x4 yv[8];
    float sc[4];

    auto half = [&](int mh) {
        __builtin_amdgcn_s_setprio(1);
#pragma unroll
        for (int mi = 0; mi < 4; ++mi)
#pragma unroll
            for (int ni = 0; ni < 4; ++ni) {
                i32x4 t = __builtin_amdgcn_mfma_i32_16x16x64_i8(a[mi][0], b[ni][0], zero, 0, 0, 0);
                t = __builtin_amdgcn_mfma_i32_16x16x64_i8(a[mi][1], b[ni][1], t, 0, 0, 0);
                f32x4& A_ = acc[mh * 4 + mi][ni];
                const f32x4& yw = yv[mh * 4 + mi];
                A_[0] += yw[0] * sc[ni] * (float)t[0];
                A_[1] += yw[1] * sc[ni] * (float)t[1];
                A_[2] += yw[2] * sc[ni] * (float)t[2];
                A_[3] += yw[3] * sc[ni] * (float)t[3];
            }
        __builtin_amdgcn_s_setprio(0);
    };
    auto loadScales = [&](int g) {
#pragma unroll
        for (int mi = 0; mi < 8; ++mi)
            yv[mi] = *(const f32x4*)(ys + (size_t)g * Mrows + rowA0 + wr * 128 + mi * 16 + kg * 4);
#pragma unroll
        for (int ni = 0; ni < 4; ++ni)
            sc[ni] = s2[(size_t)g * HH + colB0 + wc * 64 + ni * 16 + lrow];
    };

    // prologue
    stA(0, 0); stB(0, 0);
    WAIT_VM0();
    SBAR();

    const int NI = NT >> 1;
    for (int i = 0; i < NI; ++i) {
        const int c = 2 * i, n = 2 * i + 1;
        // T1
        loadScales(c);
        stA(1, n); stB(1, n);
        ldB8<0>(b, vB0, vB1);
        ldA8<0, 0>(a, vA0, vA1);
        LGKM0();
        half(0);
        ldA8<0, 1>(a, vA0, vA1);
        LGKM0();
        half(1);
        WAIT_VM0();
        SBAR();
        // T2
        loadScales(n);
        if (i < NI - 1) { stA(0, c + 2); stB(0, c + 2); }
        ldB8<32768>(b, vB0, vB1);
        ldA8<32768, 0>(a, vA0, vA1);
        LGKM0();
        half(0);
        ldA8<32768, 1>(a, vA0, vA1);
        LGKM0();
        half(1);
        WAIT_VM0();
        SBAR();
    }

    // ---- epilogue: f32, two 128-row halves via LDS, coalesced + residual
    __syncthreads();
    float* smf = (float*)SMc;
#pragma unroll
    for (int h = 0; h < 2; ++h) {
        if (wr == h) {
#pragma unroll
            for (int ni = 0; ni < 4; ++ni) {
                const int col = wc * 64 + ni * 16 + lrow;
                const float bv = bias[colB0 + col];
#pragma unroll
                for (int mi = 0; mi < 8; ++mi) {
#pragma unroll
                    for (int j = 0; j < 4; ++j) {
                        const int rowl = mi * 16 + kg * 4 + j;
                        const float v = acc[mi][ni][j] + bv;
                        smf[rowl * 256 + ((((col >> 2) ^ (rowl & 7)) << 2) | (col & 3))] = v;
                    }
                }
            }
        }
        __syncthreads();
#pragma unroll
        for (int p = 0; p < 16; ++p) {
            const int idx = p * 512 + tid;
            const int rowl = idx >> 6, s = idx & 63;
            const f32x4 v4 = *(const f32x4*)&smf[rowl * 256 + ((s ^ (rowl & 7)) << 2)];
            const size_t g = (size_t)(rowA0 + h * 128 + rowl) * HH + colB0 + s * 4;
            const float4 rv = *(const float4*)&resid[g];
            float4 o4;
            o4.x = rv.x + 0.5f * v4[0];
            o4.y = rv.y + 0.5f * v4[1];
            o4.z = rv.z + 0.5f * v4[2];
            o4.w = rv.w + 0.5f * v4[3];
            *(float4*)&out[g] = o4;
        }
        __syncthreads();
    }
}

extern "C" void kernel_launch(void* const* d_in, const int* in_sizes, int n_in,
                              void* d_out, int out_size, void* d_ws, size_t ws_size,
                              hipStream_t stream)
{
    const float* x      = (const float*)d_in[0];
    const float* gamma  = (const float*)d_in[1];
    const float* beta   = (const float*)d_in[2];
    const int*   fc1_q  = (const int*)d_in[3];
    const float* fc1_s  = (const float*)d_in[4];
    const float* fc1_b  = (const float*)d_in[5];
    const int*   fc2_q  = (const int*)d_in[6];
    const float* fc2_s  = (const float*)d_in[7];
    const float* fc2_b  = (const float*)d_in[8];
    float* out = (float*)d_out;

    char* ws = (char*)d_ws;
    char* w1q = ws;                                   // [FF][HH] int8, 4 MB
    char* w2q = ws + (size_t)FF * HH;                 // [HH][FF] int8, 4 MB
    char* base = ws + (size_t)2 * FF * HH;            // 8 MB in
    const size_t avail = ws_size - (size_t)2 * FF * HH;

    const size_t per_row = HH + FF + 4 + 128;         // hq + yq + hs + ys
    int MC = (int)(avail / per_row);
    MC = (MC / 256) * 256;
    if (MC > MTOT) MC = MTOT;
    if (MC < 256)  MC = 256;

    float* hs = (float*)base;                                  // [MC]
    float* ys = (float*)(base + (size_t)MC * 4);               // [32][MC]
    char*  hq = base + (size_t)MC * 4 + (size_t)32 * MC * 4;   // [MC][HH]
    char*  yq = hq + (size_t)MC * HH;                          // [MC][FF]

    repack_kernel<<<dim3(FF / 32, HH / 32), dim3(32, 8), 0, stream>>>(fc1_q, w1q, HH, FF);
    repack_kernel<<<dim3(HH / 32, FF / 32), dim3(32, 8), 0, stream>>>(fc2_q, w2q, FF, HH);

    for (int m0 = 0; m0 < MTOT; m0 += MC) {
        const int mc = (MTOT - m0 < MC) ? (MTOT - m0) : MC;
        ln_q_kernel<<<mc, 256, 0, stream>>>(x, gamma, beta, hq, hs, m0);
        gemm1_i8<<<dim3((FF / 256) * (mc / 256)), 512, 0, stream>>>(
            hq, w1q, fc1_s, hs, fc1_b, yq, ys, mc, FF / 256);
        gemm2_i8<<<dim3((HH / 256) * (mc / 256)), 512, 0, stream>>>(
            yq, w2q, fc2_s, ys, fc2_b, x + (size_t)m0 * HH, out + (size_t)m0 * HH,
            mc, HH / 256);
    }
}

// Round 13
// 769.974 us; speedup vs baseline: 1.0169x; 1.0169x over previous
//
#include <hip/hip_runtime.h>
#include <hip/hip_bf16.h>

#define HH 1024
#define FF 4096
#define MTOT (8 * 2048)

typedef __attribute__((ext_vector_type(4))) float f32x4;
typedef __attribute__((ext_vector_type(4))) int   i32x4;
typedef __attribute__((ext_vector_type(8))) short bf16x8;

__device__ inline void async_load16(const void* g, void* l) {
    __builtin_amdgcn_global_load_lds(
        (const __attribute__((address_space(1))) unsigned int*)g,
        (__attribute__((address_space(3))) unsigned int*)l, 16, 0, 0);
}
__device__ inline unsigned lds_off(void* p) {
    return (unsigned)(size_t)(__attribute__((address_space(3))) char*)p;
}
template<int OFF>
__device__ inline i32x4 dsr(unsigned addr) {
    i32x4 r;
    asm volatile("ds_read_b128 %0, %1 offset:%2" : "=v"(r) : "v"(addr), "n"(OFF));
    return r;
}
#define SBAR()  __builtin_amdgcn_s_barrier()
#define LGKM0() do { asm volatile("s_waitcnt lgkmcnt(0)"); \
                     __builtin_amdgcn_sched_barrier(0); } while (0)
#define WAIT_VM0() asm volatile("s_waitcnt vmcnt(0)")

__device__ inline float b2f(short s) {
    unsigned u = ((unsigned)(unsigned short)s) << 16;
    float f; __builtin_memcpy(&f, &u, 4); return f;
}
__device__ inline int q8(float f) {
    int v = __float2int_rn(f);
    return v < -127 ? -127 : (v > 127 ? 127 : v);
}

template<int B0, int MH>
__device__ inline void ldA8(i32x4 (&d)[4][2], unsigned v0, unsigned v1) {
    constexpr int B = B0 + MH * 8192;
    d[0][0] = dsr<B + 0>(v0);     d[0][1] = dsr<B + 0>(v1);
    d[1][0] = dsr<B + 2048>(v0);  d[1][1] = dsr<B + 2048>(v1);
    d[2][0] = dsr<B + 4096>(v0);  d[2][1] = dsr<B + 4096>(v1);
    d[3][0] = dsr<B + 6144>(v0);  d[3][1] = dsr<B + 6144>(v1);
}
template<int B0>
__device__ inline void ldB8(i32x4 (&d)[4][2], unsigned v0, unsigned v1) {
    d[0][0] = dsr<B0 + 0>(v0);     d[0][1] = dsr<B0 + 0>(v1);
    d[1][0] = dsr<B0 + 2048>(v0);  d[1][1] = dsr<B0 + 2048>(v1);
    d[2][0] = dsr<B0 + 4096>(v0);  d[2][1] = dsr<B0 + 4096>(v1);
    d[3][0] = dsr<B0 + 6144>(v0);  d[3][1] = dsr<B0 + 6144>(v1);
}

// ---------------- repack: q[K][N] int32 (zp=128) -> wq[N][K] int8
__global__ void repack_kernel(const int* __restrict__ q, char* __restrict__ wq,
                              int K, int N)
{
    __shared__ char tile[32][33];
    const int n0 = blockIdx.x * 32, k0 = blockIdx.y * 32;
    const int tx = threadIdx.x, ty = threadIdx.y; // (32,8)
#pragma unroll
    for (int i = 0; i < 32; i += 8)
        tile[ty + i][tx] = (char)(q[(size_t)(k0 + ty + i) * N + n0 + tx] - 128);
    __syncthreads();
#pragma unroll
    for (int i = 0; i < 32; i += 8)
        wq[(size_t)(n0 + ty + i) * K + k0 + tx] = tile[tx][ty + i];
}

// ---------------- LayerNorm + per-row int8 quant
__global__ __launch_bounds__(256)
void ln_q_kernel(const float* __restrict__ x, const float* __restrict__ gamma,
                 const float* __restrict__ beta, char* __restrict__ hq,
                 float* __restrict__ hs, int m0)
{
    const int row = m0 + blockIdx.x;
    const float4 v = ((const float4*)(x + (size_t)row * HH))[threadIdx.x];
    float s  = v.x + v.y + v.z + v.w;
    float ss = v.x * v.x + v.y * v.y + v.z * v.z + v.w * v.w;
#pragma unroll
    for (int o = 32; o > 0; o >>= 1) { s += __shfl_down(s, o); ss += __shfl_down(ss, o); }
    __shared__ float red[8];
    const int wid = threadIdx.x >> 6, lane = threadIdx.x & 63;
    if (lane == 0) { red[wid] = s; red[4 + wid] = ss; }
    __syncthreads();
    if (threadIdx.x == 0) {
        red[0] = red[0] + red[1] + red[2] + red[3];
        red[4] = red[4] + red[5] + red[6] + red[7];
    }
    __syncthreads();
    const float mu   = red[0] * (1.f / HH);
    const float rstd = rsqrtf(red[4] * (1.f / HH) - mu * mu + 1e-5f);
    const float4 g = ((const float4*)gamma)[threadIdx.x];
    const float4 b = ((const float4*)beta)[threadIdx.x];
    float h0 = (v.x - mu) * rstd * g.x + b.x;
    float h1 = (v.y - mu) * rstd * g.y + b.y;
    float h2 = (v.z - mu) * rstd * g.z + b.z;
    float h3 = (v.w - mu) * rstd * g.w + b.w;
    float mx = fmaxf(fmaxf(fabsf(h0), fabsf(h1)), fmaxf(fabsf(h2), fabsf(h3)));
#pragma unroll
    for (int o = 32; o > 0; o >>= 1) mx = fmaxf(mx, __shfl_down(mx, o));
    __syncthreads();
    if (lane == 0) red[wid] = mx;
    __syncthreads();
    if (threadIdx.x == 0)
        red[0] = fmaxf(fmaxf(red[0], red[1]), fmaxf(red[2], red[3]));
    __syncthreads();
    const float m = fmaxf(red[0], 1e-12f);
    const float inv = 127.f / m;
    const int q0 = q8(h0 * inv), q1 = q8(h1 * inv), q2 = q8(h2 * inv), q3 = q8(h3 * inv);
    ((int*)(hq + (size_t)blockIdx.x * HH))[threadIdx.x] =
        (q0 & 255) | ((q1 & 255) << 8) | ((q2 & 255) << 16) | ((q3 & 255) << 24);
    if (threadIdx.x == 0) hs[blockIdx.x] = m / 127.f;
}

// ---------------- GEMM1: yq = quant( silu(hs*(hq@w1q scaled) + b1) ), + ys per (g,row)
__global__ __launch_bounds__(512, 2)
void gemm1_i8(const char* __restrict__ A, const char* __restrict__ Bt,
              const float* __restrict__ s1, const float* __restrict__ hs,
              const float* __restrict__ bias,
              char* __restrict__ yq, float* __restrict__ ys,
              int Mrows, int nbx)
{
    constexpr int KK = HH;          // bytes per row
    constexpr int NT = KK / 128;    // 8
    __shared__ __align__(16) char SMc[131072];

    const int nwg = (int)gridDim.x, bq = (int)blockIdx.x;
    const int q = nwg >> 3, r = nwg & 7;
    const int xcd = bq & 7, pos = bq >> 3;
    const int bid = (xcd < r) ? xcd * (q + 1) + pos
                              : r * (q + 1) + (xcd - r) * q + pos;
    const int bx = bid % nbx, by = bid / nbx;
    const int rowA0 = by * 256, colB0 = bx * 256;

    const int tid = (int)threadIdx.x;
    const int lane = tid & 63, wid = tid >> 6;
    const int wr = wid >> 2, wc = wid & 3;
    const int lrow = lane & 15, kg = lane >> 4;
    const int swz = lrow & 7;

    const int srow = tid >> 3;
    const int sgs  = (tid & 7) ^ (srow & 7);
    const char* aSrc = A  + (size_t)(rowA0 + srow) * KK + sgs * 16;
    const char* bSrc = Bt + (size_t)(colB0 + srow) * KK + sgs * 16;
    char* aDst = SMc + srow * 128 + (tid & 7) * 16;
    char* bDst = SMc + 65536 + srow * 128 + (tid & 7) * 16;

    const unsigned asB = lds_off(SMc);
    const unsigned k0off = (unsigned)((kg ^ swz) << 4);
    const unsigned k1off = (unsigned)(((4 + kg) ^ swz) << 4);
    const unsigned vA0 = asB + (unsigned)((wr * 128 + lrow) * 128) + k0off;
    const unsigned vA1 = asB + (unsigned)((wr * 128 + lrow) * 128) + k1off;
    const unsigned vB0 = asB + 65536u + (unsigned)((wc * 64 + lrow) * 128) + k0off;
    const unsigned vB1 = asB + 65536u + (unsigned)((wc * 64 + lrow) * 128) + k1off;

    auto stA = [&](int buf, int t) {
        const char* s0 = aSrc + t * 128;
        char* d = aDst + buf * 32768;
        async_load16(s0, d);
        async_load16(s0 + (size_t)64 * KK,  d + 8192);
        async_load16(s0 + (size_t)128 * KK, d + 16384);
        async_load16(s0 + (size_t)192 * KK, d + 24576);
    };
    auto stB = [&](int buf, int t) {
        const char* s0 = bSrc + t * 128;
        char* d = bDst + buf * 32768;
        async_load16(s0, d);
        async_load16(s0 + (size_t)64 * KK,  d + 8192);
        async_load16(s0 + (size_t)128 * KK, d + 16384);
        async_load16(s0 + (size_t)192 * KK, d + 24576);
    };

    f32x4 acc[8][4] = {};
    const i32x4 zero = {0, 0, 0, 0};
    i32x4 a[4][2], b[4][2];
    float sc[4];

    auto half = [&](int mh) {
        __builtin_amdgcn_s_setprio(1);
#pragma unroll
        for (int mi = 0; mi < 4; ++mi)
#pragma unroll
            for (int ni = 0; ni < 4; ++ni) {
                i32x4 t = __builtin_amdgcn_mfma_i32_16x16x64_i8(a[mi][0], b[ni][0], zero, 0, 0, 0);
                t = __builtin_amdgcn_mfma_i32_16x16x64_i8(a[mi][1], b[ni][1], t, 0, 0, 0);
                f32x4& A_ = acc[mh * 4 + mi][ni];
                A_[0] += sc[ni] * (float)t[0];
                A_[1] += sc[ni] * (float)t[1];
                A_[2] += sc[ni] * (float)t[2];
                A_[3] += sc[ni] * (float)t[3];
            }
        __builtin_amdgcn_s_setprio(0);
    };

    stA(0, 0); stB(0, 0);
    WAIT_VM0();
    SBAR();

    const int NI = NT >> 1;
    for (int i = 0; i < NI; ++i) {
        const int c = 2 * i, n = 2 * i + 1;
#pragma unroll
        for (int ni = 0; ni < 4; ++ni)
            sc[ni] = s1[(size_t)c * FF + colB0 + wc * 64 + ni * 16 + lrow];
        stA(1, n); stB(1, n);
        ldB8<0>(b, vB0, vB1);
        ldA8<0, 0>(a, vA0, vA1);
        LGKM0();
        half(0);
        ldA8<0, 1>(a, vA0, vA1);
        LGKM0();
        half(1);
        WAIT_VM0();
        SBAR();
#pragma unroll
        for (int ni = 0; ni < 4; ++ni)
            sc[ni] = s1[(size_t)n * FF + colB0 + wc * 64 + ni * 16 + lrow];
        if (i < NI - 1) { stA(0, c + 2); stB(0, c + 2); }
        ldB8<32768>(b, vB0, vB1);
        ldA8<32768, 0>(a, vA0, vA1);
        LGKM0();
        half(0);
        ldA8<32768, 1>(a, vA0, vA1);
        LGKM0();
        half(1);
        WAIT_VM0();
        SBAR();
    }

    // ---- epilogue: y = silu(hs*acc + b1) -> LDS (bf16, swizzled) -> quant yq + ys
    __syncthreads();
    short* smh = (short*)SMc;
    f32x4 hv[8];
#pragma unroll
    for (int mi = 0; mi < 8; ++mi)
        hv[mi] = *(const f32x4*)(hs + rowA0 + wr * 128 + mi * 16 + kg * 4);
#pragma unroll
    for (int ni = 0; ni < 4; ++ni) {
        const int col = wc * 64 + ni * 16 + lrow;
        const float bv = bias[colB0 + col];
#pragma unroll
        for (int mi = 0; mi < 8; ++mi) {
#pragma unroll
            for (int j = 0; j < 4; ++j) {
                const int rowl = wr * 128 + mi * 16 + kg * 4 + j;
                const float v = hv[mi][j] * acc[mi][ni][j] + bv;
                const float sv = v / (1.f + __expf(-v));
                const __hip_bfloat16 hb = __float2bfloat16(sv);
                smh[rowl * 256 + ((((col >> 3) ^ (rowl & 7)) << 3) | (col & 7))] =
                    *(const short*)&hb;
            }
        }
    }
    __syncthreads();
    {
        const int rowl = tid >> 1, hf2 = tid & 1;
        const int r7 = rowl & 7;
        short* rp = smh + rowl * 256;
        float mx = 0.f;
#pragma unroll 1
        for (int u = 0; u < 16; ++u) {
            const int sslot = hf2 * 16 + u;
            const bf16x8 vv = *(const bf16x8*)(rp + ((sslot ^ r7) << 3));
#pragma unroll
            for (int e = 0; e < 8; ++e) mx = fmaxf(mx, fabsf(b2f(vv[e])));
        }
        const float mc = fmaxf(mx, 1e-12f);
        const float ysv = mc / 127.f, inv = 127.f / mc;
        ys[(size_t)(bx * 2 + hf2) * Mrows + rowA0 + rowl] = ysv;
        char* yrow = yq + (size_t)(rowA0 + rowl) * FF + colB0 + hf2 * 128;
#pragma unroll 1
        for (int u2 = 0; u2 < 8; ++u2) {
            const int s0 = hf2 * 16 + u2 * 2, s1_ = s0 + 1;
            const bf16x8 v0 = *(const bf16x8*)(rp + ((s0 ^ r7) << 3));
            const bf16x8 v1 = *(const bf16x8*)(rp + ((s1_ ^ r7) << 3));
            int w[4];
#pragma unroll
            for (int k = 0; k < 2; ++k) {
                const bf16x8& vv = k ? v1 : v0;
#pragma unroll
                for (int hq4 = 0; hq4 < 2; ++hq4) {
                    const int e0 = hq4 * 4;
                    const int a0 = q8(b2f(vv[e0 + 0]) * inv), a1 = q8(b2f(vv[e0 + 1]) * inv);
                    const int a2 = q8(b2f(vv[e0 + 2]) * inv), a3 = q8(b2f(vv[e0 + 3]) * inv);
                    w[k * 2 + hq4] = (a0 & 255) | ((a1 & 255) << 8) |
                                     ((a2 & 255) << 16) | ((a3 & 255) << 24);
                }
            }
            *(i32x4*)(yrow + u2 * 16) = (i32x4){w[0], w[1], w[2], w[3]};
        }
    }
}

// ---------------- GEMM2: out = resid + 0.5*( (yq@w2q) scaled(ys,s2) + b2 )
__global__ __launch_bounds__(512, 2)
void gemm2_i8(const char* __restrict__ A, const char* __restrict__ Bt,
              const float* __restrict__ s2, const float* __restrict__ ys,
              const float* __restrict__ bias, const float* __restrict__ resid,
              float* __restrict__ out, int Mrows, int nbx)
{
    constexpr int KK = FF;          // 4096 bytes per row
    constexpr int NT = KK / 128;    // 32
    __shared__ __align__(16) char SMc[131072];

    const int nwg = (int)gridDim.x, bq = (int)blockIdx.x;
    const int q = nwg >> 3, r = nwg & 7;
    const int xcd = bq & 7, pos = bq >> 3;
    const int bid = (xcd < r) ? xcd * (q + 1) + pos
                              : r * (q + 1) + (xcd - r) * q + pos;
    const int bx = bid % nbx, by = bid / nbx;
    const int rowA0 = by * 256, colB0 = bx * 256;

    const int tid = (int)threadIdx.x;
    const int lane = tid & 63, wid = tid >> 6;
    const int wr = wid >> 2, wc = wid & 3;
    const int lrow = lane & 15, kg = lane >> 4;
    const int swz = lrow & 7;

    const int srow = tid >> 3;
    const int sgs  = (tid & 7) ^ (srow & 7);
    const char* aSrc = A  + (size_t)(rowA0 + srow) * KK + sgs * 16;
    const char* bSrc = Bt + (size_t)(colB0 + srow) * KK + sgs * 16;
    char* aDst = SMc + srow * 128 + (tid & 7) * 16;
    char* bDst = SMc + 65536 + srow * 128 + (tid & 7) * 16;

    const unsigned asB = lds_off(SMc);
    const unsigned k0off = (unsigned)((kg ^ swz) << 4);
    const unsigned k1off = (unsigned)(((4 + kg) ^ swz) << 4);
    const unsigned vA0 = asB + (unsigned)((wr * 128 + lrow) * 128) + k0off;
    const unsigned vA1 = asB + (unsigned)((wr * 128 + lrow) * 128) + k1off;
    const unsigned vB0 = asB + 65536u + (unsigned)((wc * 64 + lrow) * 128) + k0off;
    const unsigned vB1 = asB + 65536u + (unsigned)((wc * 64 + lrow) * 128) + k1off;

    auto stA = [&](int buf, int t) {
        const char* s0 = aSrc + t * 128;
        char* d = aDst + buf * 32768;
        async_load16(s0, d);
        async_load16(s0 + (size_t)64 * KK,  d + 8192);
        async_load16(s0 + (size_t)128 * KK, d + 16384);
        async_load16(s0 + (size_t)192 * KK, d + 24576);
    };
    auto stB = [&](int buf, int t) {
        const char* s0 = bSrc + t * 128;
        char* d = bDst + buf * 32768;
        async_load16(s0, d);
        async_load16(s0 + (size_t)64 * KK,  d + 8192);
        async_load16(s0 + (size_t)128 * KK, d + 16384);
        async_load16(s0 + (size_t)192 * KK, d + 24576);
    };

    f32x4 acc[8][4] = {};
    const i32x4 zero = {0, 0, 0, 0};
    i32x4 a[4][2], b[4][2];
    float sc[4];

    // transient yw[4] (16 VGPR, live only inside the half) -- the R12 spill fix
    auto half = [&](int mh, int g) {
        f32x4 yw[4];
#pragma unroll
        for (int mi = 0; mi < 4; ++mi)
            yw[mi] = *(const f32x4*)(ys + (size_t)g * Mrows + rowA0 + wr * 128 +
                                     (mh * 4 + mi) * 16 + kg * 4);
        __builtin_amdgcn_s_setprio(1);
#pragma unroll
        for (int mi = 0; mi < 4; ++mi)
#pragma unroll
            for (int ni = 0; ni < 4; ++ni) {
                i32x4 t = __builtin_amdgcn_mfma_i32_16x16x64_i8(a[mi][0], b[ni][0], zero, 0, 0, 0);
                t = __builtin_amdgcn_mfma_i32_16x16x64_i8(a[mi][1], b[ni][1], t, 0, 0, 0);
                f32x4& A_ = acc[mh * 4 + mi][ni];
                A_[0] += yw[mi][0] * sc[ni] * (float)t[0];
                A_[1] += yw[mi][1] * sc[ni] * (float)t[1];
                A_[2] += yw[mi][2] * sc[ni] * (float)t[2];
                A_[3] += yw[mi][3] * sc[ni] * (float)t[3];
            }
        __builtin_amdgcn_s_setprio(0);
    };
    auto loadSc = [&](int g) {
#pragma unroll
        for (int ni = 0; ni < 4; ++ni)
            sc[ni] = s2[(size_t)g * HH + colB0 + wc * 64 + ni * 16 + lrow];
    };

    stA(0, 0); stB(0, 0);
    WAIT_VM0();
    SBAR();

    const int NI = NT >> 1;
    for (int i = 0; i < NI; ++i) {
        const int c = 2 * i, n = 2 * i + 1;
        loadSc(c);
        stA(1, n); stB(1, n);
        ldB8<0>(b, vB0, vB1);
        ldA8<0, 0>(a, vA0, vA1);
        LGKM0();
        half(0, c);
        ldA8<0, 1>(a, vA0, vA1);
        LGKM0();
        half(1, c);
        WAIT_VM0();
        SBAR();
        loadSc(n);
        if (i < NI - 1) { stA(0, c + 2); stB(0, c + 2); }
        ldB8<32768>(b, vB0, vB1);
        ldA8<32768, 0>(a, vA0, vA1);
        LGKM0();
        half(0, n);
        ldA8<32768, 1>(a, vA0, vA1);
        LGKM0();
        half(1, n);
        WAIT_VM0();
        SBAR();
    }

    // ---- epilogue: f32, two 128-row halves via LDS, coalesced + residual
    __syncthreads();
    float* smf = (float*)SMc;
#pragma unroll
    for (int h = 0; h < 2; ++h) {
        if (wr == h) {
#pragma unroll
            for (int ni = 0; ni < 4; ++ni) {
                const int col = wc * 64 + ni * 16 + lrow;
                const float bv = bias[colB0 + col];
#pragma unroll
                for (int mi = 0; mi < 8; ++mi) {
#pragma unroll
                    for (int j = 0; j < 4; ++j) {
                        const int rowl = mi * 16 + kg * 4 + j;
                        const float v = acc[mi][ni][j] + bv;
                        smf[rowl * 256 + ((((col >> 2) ^ (rowl & 7)) << 2) | (col & 3))] = v;
                    }
                }
            }
        }
        __syncthreads();
#pragma unroll 1
        for (int p = 0; p < 16; ++p) {
            const int idx = p * 512 + tid;
            const int rowl = idx >> 6, s = idx & 63;
            const f32x4 v4 = *(const f32x4*)&smf[rowl * 256 + ((s ^ (rowl & 7)) << 2)];
            const size_t g = (size_t)(rowA0 + h * 128 + rowl) * HH + colB0 + s * 4;
            const float4 rv = *(const float4*)&resid[g];
            float4 o4;
            o4.x = rv.x + 0.5f * v4[0];
            o4.y = rv.y + 0.5f * v4[1];
            o4.z = rv.z + 0.5f * v4[2];
            o4.w = rv.w + 0.5f * v4[3];
            *(float4*)&out[g] = o4;
        }
        __syncthreads();
    }
}

extern "C" void kernel_launch(void* const* d_in, const int* in_sizes, int n_in,
                              void* d_out, int out_size, void* d_ws, size_t ws_size,
                              hipStream_t stream)
{
    const float* x      = (const float*)d_in[0];
    const float* gamma  = (const float*)d_in[1];
    const float* beta   = (const float*)d_in[2];
    const int*   fc1_q  = (const int*)d_in[3];
    const float* fc1_s  = (const float*)d_in[4];
    const float* fc1_b  = (const float*)d_in[5];
    const int*   fc2_q  = (const int*)d_in[6];
    const float* fc2_s  = (const float*)d_in[7];
    const float* fc2_b  = (const float*)d_in[8];
    float* out = (float*)d_out;

    char* ws = (char*)d_ws;
    char* w1q = ws;                                   // [FF][HH] int8, 4 MB
    char* w2q = ws + (size_t)FF * HH;                 // [HH][FF] int8, 4 MB
    char* base = ws + (size_t)2 * FF * HH;            // 8 MB in
    const size_t avail = ws_size - (size_t)2 * FF * HH;

    const size_t per_row = HH + FF + 4 + 128;         // hq + yq + hs + ys
    int MC = (int)(avail / per_row);
    MC = (MC / 256) * 256;
    if (MC > MTOT) MC = MTOT;
    if (MC < 256)  MC = 256;

    float* hs = (float*)base;                                  // [MC]
    float* ys = (float*)(base + (size_t)MC * 4);               // [32][MC]
    char*  hq = base + (size_t)MC * 4 + (size_t)32 * MC * 4;   // [MC][HH]
    char*  yq = hq + (size_t)MC * HH;                          // [MC][FF]

    repack_kernel<<<dim3(FF / 32, HH / 32), dim3(32, 8), 0, stream>>>(fc1_q, w1q, HH, FF);
    repack_kernel<<<dim3(HH / 32, FF / 32), dim3(32, 8), 0, stream>>>(fc2_q, w2q, FF, HH);

    for (int m0 = 0; m0 < MTOT; m0 += MC) {
        const int mc = (MTOT - m0 < MC) ? (MTOT - m0) : MC;
        ln_q_kernel<<<mc, 256, 0, stream>>>(x, gamma, beta, hq, hs, m0);
        gemm1_i8<<<dim3((FF / 256) * (mc / 256)), 512, 0, stream>>>(
            hq, w1q, fc1_s, hs, fc1_b, yq, ys, mc, FF / 256);
        gemm2_i8<<<dim3((HH / 256) * (mc / 256)), 512, 0, stream>>>(
            yq, w2q, fc2_s, ys, fc2_b, x + (size_t)m0 * HH, out + (size_t)m0 * HH,
            mc, HH / 256);
    }
}

// Round 14
// 337.188 us; speedup vs baseline: 2.3222x; 2.2835x over previous
//
#include <hip/hip_runtime.h>
#include <hip/hip_bf16.h>

#define HH 1024
#define FF 4096
#define MTOT (8 * 2048)

typedef __attribute__((ext_vector_type(4))) float f32x4;
typedef __attribute__((ext_vector_type(8))) short bf16x8;

__device__ inline void async_load16(const void* g, void* l) {
    __builtin_amdgcn_global_load_lds(
        (const __attribute__((address_space(1))) unsigned int*)g,
        (__attribute__((address_space(3))) unsigned int*)l, 16, 0, 0);
}
__device__ inline unsigned lds_off(void* p) {
    return (unsigned)(size_t)(__attribute__((address_space(3))) char*)p;
}
template<int OFF>
__device__ inline bf16x8 dsr(unsigned addr) {
    bf16x8 r;
    asm volatile("ds_read_b128 %0, %1 offset:%2" : "=v"(r) : "v"(addr), "n"(OFF));
    return r;
}
// bare waits (no "memory" clobber)
#define SBAR()  __builtin_amdgcn_s_barrier()
#define LGKM0() do { asm volatile("s_waitcnt lgkmcnt(0)"); \
                     __builtin_amdgcn_sched_barrier(0); } while (0)
#define WAIT_VM0() asm volatile("s_waitcnt vmcnt(0)")

// frag loads: base VGPR (region base included) + buf/frag compile-time offset.
// Both A and B regions: buf stride 16384 B, frag stride 2048 B (16 rows x 128 B).
template<int BUF>
__device__ inline void ldF(bf16x8 (&d)[4][2], unsigned v0, unsigned v1) {
    constexpr int B = BUF * 16384;
    d[0][0] = dsr<B + 0>(v0);     d[0][1] = dsr<B + 0>(v1);
    d[1][0] = dsr<B + 2048>(v0);  d[1][1] = dsr<B + 2048>(v1);
    d[2][0] = dsr<B + 4096>(v0);  d[2][1] = dsr<B + 4096>(v1);
    d[3][0] = dsr<B + 6144>(v0);  d[3][1] = dsr<B + 6144>(v1);
}

// ---------------- dequant + transpose: q[K][N], scales[K/128][N] -> wt[N][K] bf16
__global__ void dequant_t_kernel(const int* __restrict__ q,
                                 const float* __restrict__ scales,
                                 __hip_bfloat16* __restrict__ wt,
                                 int K, int N)
{
    __shared__ float tile[32][33];
    const int n0 = blockIdx.x * 32, k0 = blockIdx.y * 32;
    const int tx = threadIdx.x, ty = threadIdx.y; // (32,8)
#pragma unroll
    for (int i = 0; i < 32; i += 8) {
        int k = k0 + ty + i, n = n0 + tx;
        float s = scales[(size_t)(k >> 7) * N + n];
        tile[ty + i][tx] = (float)(q[(size_t)k * N + n] - 128) * s;
    }
    __syncthreads();
#pragma unroll
    for (int i = 0; i < 32; i += 8) {
        int n = n0 + ty + i, k = k0 + tx;
        wt[(size_t)n * K + k] = __float2bfloat16(tile[tx][ty + i]);
    }
}

// ---------------- LayerNorm
__global__ __launch_bounds__(256)
void ln_kernel(const float* __restrict__ x, const float* __restrict__ gamma,
               const float* __restrict__ beta, __hip_bfloat16* __restrict__ hf,
               int m0)
{
    const int row = m0 + blockIdx.x;
    const float4 v = ((const float4*)(x + (size_t)row * HH))[threadIdx.x];
    float s  = v.x + v.y + v.z + v.w;
    float ss = v.x * v.x + v.y * v.y + v.z * v.z + v.w * v.w;
#pragma unroll
    for (int o = 32; o > 0; o >>= 1) { s += __shfl_down(s, o); ss += __shfl_down(ss, o); }
    __shared__ float red[8];
    const int wid = threadIdx.x >> 6, lane = threadIdx.x & 63;
    if (lane == 0) { red[wid] = s; red[4 + wid] = ss; }
    __syncthreads();
    if (threadIdx.x == 0) {
        red[0] = red[0] + red[1] + red[2] + red[3];
        red[4] = red[4] + red[5] + red[6] + red[7];
    }
    __syncthreads();
    const float mu   = red[0] * (1.f / HH);
    const float rstd = rsqrtf(red[4] * (1.f / HH) - mu * mu + 1e-5f);
    const float4 g = ((const float4*)gamma)[threadIdx.x];
    const float4 b = ((const float4*)beta)[threadIdx.x];
    float h0 = (v.x - mu) * rstd * g.x + b.x;
    float h1 = (v.y - mu) * rstd * g.y + b.y;
    float h2 = (v.z - mu) * rstd * g.z + b.z;
    float h3 = (v.w - mu) * rstd * g.w + b.w;
    __hip_bfloat16 t0 = __float2bfloat16(h0), t1 = __float2bfloat16(h1);
    __hip_bfloat16 t2 = __float2bfloat16(h2), t3 = __float2bfloat16(h3);
    ushort4 o;
    o.x = *(unsigned short*)&t0; o.y = *(unsigned short*)&t1;
    o.z = *(unsigned short*)&t2; o.w = *(unsigned short*)&t3;
    ((ushort4*)(hf + (size_t)blockIdx.x * HH))[threadIdx.x] = o;
}

// ---------------- 128x128 bf16 MFMA GEMM, 2 blocks/CU, R11 rhythm, Bt [N][K]
// EPI=0: out = bf16( silu(acc + bias) )     EPI=1: out = resid + 0.5f*(acc+bias)  (f32)
template<int EPI, int KK>
__global__ __launch_bounds__(256, 2)
void gemm128(const __hip_bfloat16* __restrict__ A,
             const __hip_bfloat16* __restrict__ Bt,
             const float* __restrict__ bias,
             const float* __restrict__ resid,
             void* __restrict__ outv,
             int N, int nbx)
{
    // 64 KiB LDS: A-buf0 @0, A-buf1 @16384B, B-buf0 @32768B, B-buf1 @49152B
    __shared__ __align__(16) short SM[32768];
    constexpr int NT = KK >> 6;

    // bijective XCD swizzle (m204)
    const int nwg = (int)gridDim.x, b = (int)blockIdx.x;
    const int q = nwg >> 3, r = nwg & 7;
    const int xcd = b & 7, pos = b >> 3;
    const int bid = (xcd < r) ? xcd * (q + 1) + pos
                              : r * (q + 1) + (xcd - r) * q + pos;
    const int bx = bid % nbx, by = bid / nbx;
    const int rowA0 = by * 128, colB0 = bx * 128;

    const int tid = (int)threadIdx.x;
    const int lane = tid & 63, wid = tid >> 6;
    const int wr = wid >> 1, wc = wid & 1;       // 2x2 wave grid
    const int lrow = lane & 15, kg = lane >> 4;
    const int swz = lrow & 7;

    // staging: thread t covers (row = t/8 in 0..31, 16B slot = t%8); 4 chunks of 32 rows
    const int srow = tid >> 3;
    const int sgs  = (tid & 7) ^ (srow & 7);     // (row+32m)&7 == row&7 -> same all chunks
    const __hip_bfloat16* aSrc = A  + (size_t)(rowA0 + srow) * KK + sgs * 8;
    const __hip_bfloat16* bSrc = Bt + (size_t)(colB0 + srow) * KK + sgs * 8;
    short* aDst = SM + srow * 64 + (tid & 7) * 8;
    short* bDst = SM + 16384 + srow * 64 + (tid & 7) * 8;

    // frag-read bases (row stride 128 B, same swizzle as R11 -> 0 conflicts)
    const unsigned asB = lds_off(SM);
    const unsigned k0off = (unsigned)((kg ^ swz) << 4);
    const unsigned k1off = (unsigned)(((4 + kg) ^ swz) << 4);
    const unsigned vA0 = asB + (unsigned)((wr * 64 + lrow) * 128) + k0off;
    const unsigned vA1 = asB + (unsigned)((wr * 64 + lrow) * 128) + k1off;
    const unsigned vB0 = asB + 32768u + (unsigned)((wc * 64 + lrow) * 128) + k0off;
    const unsigned vB1 = asB + 32768u + (unsigned)((wc * 64 + lrow) * 128) + k1off;

    auto stA = [&](int buf, int t) {             // full 128x64 tile: 4 loads
        const __hip_bfloat16* s0 = aSrc + (size_t)t * 64;
        short* d = aDst + buf * 8192;
        async_load16(s0,                    d);
        async_load16(s0 + (size_t)32 * KK,  d + 2048);
        async_load16(s0 + (size_t)64 * KK,  d + 4096);
        async_load16(s0 + (size_t)96 * KK,  d + 6144);
    };
    auto stB = [&](int buf, int t) {
        const __hip_bfloat16* s0 = bSrc + (size_t)t * 64;
        short* d = bDst + buf * 8192;
        async_load16(s0,                    d);
        async_load16(s0 + (size_t)32 * KK,  d + 2048);
        async_load16(s0 + (size_t)64 * KK,  d + 4096);
        async_load16(s0 + (size_t)96 * KK,  d + 6144);
    };

    f32x4 acc[4][4] = {};
    bf16x8 a[4][2], bb[4][2];
    auto mfall = [&]() {
        __builtin_amdgcn_s_setprio(1);
#pragma unroll
        for (int ks = 0; ks < 2; ++ks)
#pragma unroll
            for (int mi = 0; mi < 4; ++mi)
#pragma unroll
                for (int ni = 0; ni < 4; ++ni)
                    acc[mi][ni] = __builtin_amdgcn_mfma_f32_16x16x32_bf16(
                        a[mi][ks], bb[ni][ks], acc[mi][ni], 0, 0, 0);
        __builtin_amdgcn_s_setprio(0);
    };

    // prologue: buf0 <- tile 0
    stA(0, 0); stB(0, 0);
    WAIT_VM0();
    SBAR();

    const int NI = NT >> 1;
    for (int i = 0; i < NI; ++i) {
        const int c = 2 * i, n = 2 * i + 1;
        // T1: compute buf0 (tile c); stage buf1 <- tile n
        stA(1, n); stB(1, n);
        ldF<0>(bb, vB0, vB1);
        ldF<0>(a, vA0, vA1);
        LGKM0();
        mfall();
        WAIT_VM0();
        SBAR();
        // T2: compute buf1 (tile n); stage buf0 <- tile c+2
        if (i < NI - 1) { stA(0, c + 2); stB(0, c + 2); }
        ldF<1>(bb, vB0, vB1);
        ldF<1>(a, vA0, vA1);
        LGKM0();
        mfall();
        WAIT_VM0();
        SBAR();
    }

    // -------- epilogue: LDS-staged, fully coalesced --------
    __syncthreads();
    if (EPI == 0) {
        short* smh = SM;   // 128 x 128 bf16 = 32 KiB
#pragma unroll
        for (int ni = 0; ni < 4; ++ni) {
            const int col = wc * 64 + ni * 16 + lrow;
            const float bv = bias[colB0 + col];
#pragma unroll
            for (int mi = 0; mi < 4; ++mi) {
#pragma unroll
                for (int j = 0; j < 4; ++j) {
                    const int rowl = wr * 64 + mi * 16 + kg * 4 + j;
                    const float v = acc[mi][ni][j] + bv;
                    const float sv = v / (1.f + __expf(-v));
                    const __hip_bfloat16 hb = __float2bfloat16(sv);
                    smh[rowl * 128 + ((((col >> 3) ^ (rowl & 7)) << 3) | (col & 7))] =
                        *(const short*)&hb;
                }
            }
        }
        __syncthreads();
        __hip_bfloat16* yp = (__hip_bfloat16*)outv;
#pragma unroll
        for (int p = 0; p < 8; ++p) {
            const int idx = p * 256 + tid;
            const int rowl = idx >> 4, s = idx & 15;
            const bf16x8 v8 = *(const bf16x8*)&smh[rowl * 128 + ((s ^ (rowl & 7)) << 3)];
            *(bf16x8*)(yp + (size_t)(rowA0 + rowl) * N + colB0 + s * 8) = v8;
        }
    } else {
        float* smf = (float*)SM;   // 128 x 128 f32 = 64 KiB
        float* op = (float*)outv;
#pragma unroll
        for (int ni = 0; ni < 4; ++ni) {
            const int col = wc * 64 + ni * 16 + lrow;
            const float bv = bias[colB0 + col];
#pragma unroll
            for (int mi = 0; mi < 4; ++mi) {
#pragma unroll
                for (int j = 0; j < 4; ++j) {
                    const int rowl = wr * 64 + mi * 16 + kg * 4 + j;
                    const float v = acc[mi][ni][j] + bv;
                    smf[rowl * 128 + ((((col >> 2) ^ (rowl & 7)) << 2) | (col & 3))] = v;
                }
            }
        }
        __syncthreads();
#pragma unroll
        for (int p = 0; p < 16; ++p) {
            const int idx = p * 256 + tid;
            const int rowl = idx >> 5, s = idx & 31;
            const f32x4 v4 = *(const f32x4*)&smf[rowl * 128 + ((s ^ (rowl & 7)) << 2)];
            const size_t g = (size_t)(rowA0 + rowl) * N + colB0 + s * 4;
            const float4 rv = *(const float4*)&resid[g];
            float4 o4;
            o4.x = rv.x + 0.5f * v4[0];
            o4.y = rv.y + 0.5f * v4[1];
            o4.z = rv.z + 0.5f * v4[2];
            o4.w = rv.w + 0.5f * v4[3];
            *(float4*)&op[g] = o4;
        }
    }
}

extern "C" void kernel_launch(void* const* d_in, const int* in_sizes, int n_in,
                              void* d_out, int out_size, void* d_ws, size_t ws_size,
                              hipStream_t stream)
{
    const float* x      = (const float*)d_in[0];
    const float* gamma  = (const float*)d_in[1];
    const float* beta   = (const float*)d_in[2];
    const int*   fc1_q  = (const int*)d_in[3];
    const float* fc1_s  = (const float*)d_in[4];
    const float* fc1_b  = (const float*)d_in[5];
    const int*   fc2_q  = (const int*)d_in[6];
    const float* fc2_s  = (const float*)d_in[7];
    const float* fc2_b  = (const float*)d_in[8];
    float* out = (float*)d_out;

    char* ws = (char*)d_ws;
    __hip_bfloat16* w1t = (__hip_bfloat16*)ws;                            // [F][H]
    __hip_bfloat16* w2t = (__hip_bfloat16*)(ws + (size_t)FF * HH * 2);    // [H][F]
    char* dyn = ws + (size_t)2 * FF * HH * 2;
    const size_t avail = ws_size - (size_t)2 * FF * HH * 2;

    int MC = (int)(avail / ((size_t)(HH + FF) * 2));
    MC = (MC / 256) * 256;
    if (MC > MTOT) MC = MTOT;
    if (MC < 256)  MC = 256;

    __hip_bfloat16* hf_c = (__hip_bfloat16*)dyn;
    __hip_bfloat16* y_c  = (__hip_bfloat16*)(dyn + (size_t)MC * HH * 2);

    dequant_t_kernel<<<dim3(FF / 32, HH / 32), dim3(32, 8), 0, stream>>>(
        fc1_q, fc1_s, w1t, HH, FF);
    dequant_t_kernel<<<dim3(HH / 32, FF / 32), dim3(32, 8), 0, stream>>>(
        fc2_q, fc2_s, w2t, FF, HH);

    for (int m0 = 0; m0 < MTOT; m0 += MC) {
        const int mc = (MTOT - m0 < MC) ? (MTOT - m0) : MC;
        ln_kernel<<<mc, 256, 0, stream>>>(x, gamma, beta, hf_c, m0);
        gemm128<0, HH><<<dim3((FF / 128) * (mc / 128)), 256, 0, stream>>>(
            hf_c, w1t, fc1_b, nullptr, (void*)y_c, FF, FF / 128);
        gemm128<1, FF><<<dim3((HH / 128) * (mc / 128)), 256, 0, stream>>>(
            y_c, w2t, fc2_b, x + (size_t)m0 * HH, (void*)(out + (size_t)m0 * HH),
            HH, HH / 128);
    }
}

// Round 15
// 313.320 us; speedup vs baseline: 2.4991x; 1.0762x over previous
//
#include <hip/hip_runtime.h>
#include <hip/hip_bf16.h>

#define HH 1024
#define FF 4096
#define MTOT (8 * 2048)

typedef __attribute__((ext_vector_type(4))) float f32x4;
typedef __attribute__((ext_vector_type(8))) short bf16x8;

__device__ inline void async_load16(const void* g, void* l) {
    __builtin_amdgcn_global_load_lds(
        (const __attribute__((address_space(1))) unsigned int*)g,
        (__attribute__((address_space(3))) unsigned int*)l, 16, 0, 0);
}
__device__ inline unsigned lds_off(void* p) {
    return (unsigned)(size_t)(__attribute__((address_space(3))) char*)p;
}
template<int OFF>
__device__ inline bf16x8 dsr(unsigned addr) {
    bf16x8 r;
    asm volatile("ds_read_b128 %0, %1 offset:%2" : "=v"(r) : "v"(addr), "n"(OFF));
    return r;
}
// bare waits (no "memory" clobber)
#define SBAR()  __builtin_amdgcn_s_barrier()
#define LGKM0() do { asm volatile("s_waitcnt lgkmcnt(0)"); \
                     __builtin_amdgcn_sched_barrier(0); } while (0)
#define WAIT_VM0() asm volatile("s_waitcnt vmcnt(0)")

// ds_read fragment loads: base VGPR + compile-time offset only
template<int BUF, int MH>
__device__ inline void ldA(bf16x8 (&d)[4][2], unsigned vA0, unsigned vA1) {
    constexpr int B = BUF * 32768 + MH * 8192;
    d[0][0] = dsr<B + 0>(vA0);     d[0][1] = dsr<B + 0>(vA1);
    d[1][0] = dsr<B + 2048>(vA0);  d[1][1] = dsr<B + 2048>(vA1);
    d[2][0] = dsr<B + 4096>(vA0);  d[2][1] = dsr<B + 4096>(vA1);
    d[3][0] = dsr<B + 6144>(vA0);  d[3][1] = dsr<B + 6144>(vA1);
}
template<int BUF, int NH>
__device__ inline void ldB(bf16x8 (&d)[2][2], unsigned vB0, unsigned vB1) {
    constexpr int B = BUF * 32768 + NH * 4096;
    d[0][0] = dsr<B + 0>(vB0);     d[0][1] = dsr<B + 0>(vB1);
    d[1][0] = dsr<B + 2048>(vB0);  d[1][1] = dsr<B + 2048>(vB1);
}

// ---------------- dequant + transpose: q[K][N], scales[K/128][N] -> wt[N][K] bf16
__global__ void dequant_t_kernel(const int* __restrict__ q,
                                 const float* __restrict__ scales,
                                 __hip_bfloat16* __restrict__ wt,
                                 int K, int N)
{
    __shared__ float tile[32][33];
    const int n0 = blockIdx.x * 32, k0 = blockIdx.y * 32;
    const int tx = threadIdx.x, ty = threadIdx.y; // (32,8)
#pragma unroll
    for (int i = 0; i < 32; i += 8) {
        int k = k0 + ty + i, n = n0 + tx;
        float s = scales[(size_t)(k >> 7) * N + n];
        tile[ty + i][tx] = (float)(q[(size_t)k * N + n] - 128) * s;
    }
    __syncthreads();
#pragma unroll
    for (int i = 0; i < 32; i += 8) {
        int n = n0 + ty + i, k = k0 + tx;
        wt[(size_t)n * K + k] = __float2bfloat16(tile[tx][ty + i]);
    }
}

// ---------------- LayerNorm
__global__ __launch_bounds__(256)
void ln_kernel(const float* __restrict__ x, const float* __restrict__ gamma,
               const float* __restrict__ beta, __hip_bfloat16* __restrict__ hf,
               int m0)
{
    const int row = m0 + blockIdx.x;
    const float4 v = ((const float4*)(x + (size_t)row * HH))[threadIdx.x];
    float s  = v.x + v.y + v.z + v.w;
    float ss = v.x * v.x + v.y * v.y + v.z * v.z + v.w * v.w;
#pragma unroll
    for (int o = 32; o > 0; o >>= 1) { s += __shfl_down(s, o); ss += __shfl_down(ss, o); }
    __shared__ float red[8];
    const int wid = threadIdx.x >> 6, lane = threadIdx.x & 63;
    if (lane == 0) { red[wid] = s; red[4 + wid] = ss; }
    __syncthreads();
    if (threadIdx.x == 0) {
        red[0] = red[0] + red[1] + red[2] + red[3];
        red[4] = red[4] + red[5] + red[6] + red[7];
    }
    __syncthreads();
    const float mu   = red[0] * (1.f / HH);
    const float rstd = rsqrtf(red[4] * (1.f / HH) - mu * mu + 1e-5f);
    const float4 g = ((const float4*)gamma)[threadIdx.x];
    const float4 b = ((const float4*)beta)[threadIdx.x];
    float h0 = (v.x - mu) * rstd * g.x + b.x;
    float h1 = (v.y - mu) * rstd * g.y + b.y;
    float h2 = (v.z - mu) * rstd * g.z + b.z;
    float h3 = (v.w - mu) * rstd * g.w + b.w;
    __hip_bfloat16 t0 = __float2bfloat16(h0), t1 = __float2bfloat16(h1);
    __hip_bfloat16 t2 = __float2bfloat16(h2), t3 = __float2bfloat16(h3);
    ushort4 o;
    o.x = *(unsigned short*)&t0; o.y = *(unsigned short*)&t1;
    o.z = *(unsigned short*)&t2; o.w = *(unsigned short*)&t3;
    ((ushort4*)(hf + (size_t)blockIdx.x * HH))[threadIdx.x] = o;
}

// ---------------- 256x256 bf16 MFMA GEMM, R11 rhythm + 2D supertile XCD swizzle
// EPI=0: out = bf16( silu(acc + bias) )     EPI=1: out = resid + 0.5f*(acc+bias)  (f32)
template<int EPI, int KK>
__global__ __launch_bounds__(512, 2)
void gemm256(const __hip_bfloat16* __restrict__ A,
             const __hip_bfloat16* __restrict__ Bt,
             const float* __restrict__ bias,
             const float* __restrict__ resid,
             void* __restrict__ outv,
             int N, int nbx)
{
    // unified 128 KiB LDS: As = SM[0..32767], Bs = SM[32768..65535] (shorts)
    __shared__ __align__(16) short SM[65536];
    constexpr int NT = KK >> 6;

    // ---- block -> (bx,by): 2D supertile XCD swizzle (4 bx x 8 by = 32 blocks/XCD
    // concurrent working set = 4 B-panels + 8 A-panels, L2-resident). Fallback: m204.
    const int nwg = (int)gridDim.x, b = (int)blockIdx.x;
    const int nby = nwg / nbx;
    int bx, by;
    if (((nwg & 255) == 0) && ((nbx & 3) == 0) && ((nby & 7) == 0)) {
        const int x = b & 7, p = b >> 3;
        const int s = (p >> 5) * 8 + x;      // supertile id for this XCD
        const int t = p & 31;                // index within 32-block supertile
        const int sbx = nbx >> 2;            // supertiles across bx
        bx = (s % sbx) * 4 + (t & 3);
        by = (s / sbx) * 8 + (t >> 2);
    } else {
        const int q = nwg >> 3, r = nwg & 7;
        const int xcd = b & 7, pos = b >> 3;
        const int bid = (xcd < r) ? xcd * (q + 1) + pos
                                  : r * (q + 1) + (xcd - r) * q + pos;
        bx = bid % nbx; by = bid / nbx;
    }
    const int rowA0 = by * 256, colB0 = bx * 256;

    const int tid = (int)threadIdx.x;
    const int lane = tid & 63, wid = tid >> 6;
    const int wr = wid >> 2, wc = wid & 3;       // 2x4 wave grid
    const int lrow = lane & 15, kg = lane >> 4;
    const int swz = lrow & 7;

    // staging: thread t covers (row = t/8, 16B slot = t%8), source pre-inverse-swizzled
    const int srow = tid >> 3;
    const int sgs  = (tid & 7) ^ (srow & 7);
    const __hip_bfloat16* aSrc = A  + (size_t)(rowA0 + srow) * KK + sgs * 8;
    const __hip_bfloat16* bSrc = Bt + (size_t)(colB0 + srow) * KK + sgs * 8;
    short* aDst = SM + srow * 64 + (tid & 7) * 8;
    short* bDst = SM + 32768 + srow * 64 + (tid & 7) * 8;

    // precomputed ds_read bases
    const unsigned asB = lds_off(SM);
    const unsigned k0off = (unsigned)((kg ^ swz) << 4);
    const unsigned k1off = (unsigned)(((4 + kg) ^ swz) << 4);
    const unsigned vA0 = asB + (unsigned)((wr * 128 + lrow) * 128) + k0off;
    const unsigned vA1 = asB + (unsigned)((wr * 128 + lrow) * 128) + k1off;
    const unsigned vB0 = asB + 65536u + (unsigned)((wc * 64 + lrow) * 128) + k0off;
    const unsigned vB1 = asB + 65536u + (unsigned)((wc * 64 + lrow) * 128) + k1off;

    auto stA = [&](int buf, int t, int half) {    // one A half-tile: 2 loads
        const size_t ko = (size_t)t * 64;
        short* d = aDst + buf * 16384 + half * 8192;
        const __hip_bfloat16* s0 = aSrc + (size_t)(half * 128) * KK + ko;
        async_load16(s0, d);
        async_load16(s0 + (size_t)64 * KK, d + 4096);
    };
    auto stB = [&](int buf, int t, int half) {    // one B half-tile: 2 loads
        const size_t ko = (size_t)t * 64;
        short* d = bDst + buf * 16384 + half * 8192;
        const __hip_bfloat16* s0 = bSrc + (size_t)(half * 128) * KK + ko;
        async_load16(s0, d);
        async_load16(s0 + (size_t)64 * KK, d + 4096);
    };

    f32x4 acc[8][4] = {};
    auto mf = [&](const bf16x8 (&a)[4][2], const bf16x8 (&bb)[2][2], int mh, int nh) {
        __builtin_amdgcn_s_setprio(1);
#pragma unroll
        for (int ks = 0; ks < 2; ++ks)
#pragma unroll
            for (int m2 = 0; m2 < 4; ++m2)
#pragma unroll
                for (int n2 = 0; n2 < 2; ++n2)
                    acc[mh * 4 + m2][nh * 2 + n2] =
                        __builtin_amdgcn_mfma_f32_16x16x32_bf16(
                            a[m2][ks], bb[n2][ks], acc[mh * 4 + m2][nh * 2 + n2], 0, 0, 0);
        __builtin_amdgcn_s_setprio(0);
    };

    // -------- prologue: buf0 <- tile 0 (16 loads); drain; barrier
    stA(0, 0, 0); stA(0, 0, 1); stB(0, 0, 0); stB(0, 0, 1);
    WAIT_VM0();
    SBAR();

    bf16x8 a0[4][2], a1[4][2], b0[2][2], b1[2][2];
    const int NI = NT >> 1;
    for (int i = 0; i < NI; ++i) {
        const int c = 2 * i, n = 2 * i + 1;
        // ================= T1: tile c (buf0); stage buf1 <- tile n =================
        stA(1, n, 0); stA(1, n, 1); stB(1, n, 0); stB(1, n, 1);
        ldA<0, 0>(a0, vA0, vA1);   // reads 1-8
        ldB<0, 0>(b0, vB0, vB1);   // reads 9-12
        ldB<0, 1>(b1, vB0, vB1);   // reads 13-16
        ldA<0, 1>(a1, vA0, vA1);   // reads 17-24
        LGKM0();
        mf(a0, b0, 0, 0);
        mf(a0, b1, 0, 1);
        mf(a1, b0, 1, 0);
        mf(a1, b1, 1, 1);
        WAIT_VM0();                 // staged loads (issued ~whole phase ago) done
        SBAR();                     // all waves drained -> buf1 readable, buf0 free
        // ================= T2: tile n (buf1); stage buf0 <- tile c+2 ===============
        if (i < NI - 1) { stA(0, c + 2, 0); stA(0, c + 2, 1);
                          stB(0, c + 2, 0); stB(0, c + 2, 1); }
        ldA<1, 0>(a0, vA0, vA1);
        ldB<1, 0>(b0, vB0, vB1);
        ldB<1, 1>(b1, vB0, vB1);
        ldA<1, 1>(a1, vA0, vA1);
        LGKM0();
        mf(a0, b0, 0, 0);
        mf(a0, b1, 0, 1);
        mf(a1, b0, 1, 0);
        mf(a1, b1, 1, 1);
        WAIT_VM0();
        SBAR();
    }

    // -------- epilogue: LDS-staged, fully coalesced global writes --------
    __syncthreads();   // real fence: all waves done with SM before restaging

    if (EPI == 0) {
        // bf16 tile 256 rows x 512 B = 128 KiB, XOR-slot swizzle (8-col slots)
        short* smh = SM;
#pragma unroll
        for (int ni = 0; ni < 4; ++ni) {
            const int col = wc * 64 + ni * 16 + lrow;
            const float bv = bias[colB0 + col];
#pragma unroll
            for (int mi = 0; mi < 8; ++mi) {
#pragma unroll
                for (int j = 0; j < 4; ++j) {
                    const int rowl = wr * 128 + mi * 16 + kg * 4 + j;
                    const float v = acc[mi][ni][j] + bv;
                    const float sv = v / (1.f + __expf(-v));
                    const __hip_bfloat16 hb = __float2bfloat16(sv);
                    const int sidx = rowl * 256 + ((((col >> 3) ^ (rowl & 7)) << 3) | (col & 7));
                    smh[sidx] = *(const short*)&hb;
                }
            }
        }
        __syncthreads();
        __hip_bfloat16* yp = (__hip_bfloat16*)outv;
#pragma unroll
        for (int p = 0; p < 16; ++p) {
            const int idx = p * 512 + tid;
            const int rowl = idx >> 5, s = idx & 31;
            const bf16x8 v8 = *(const bf16x8*)&smh[rowl * 256 + ((s ^ (rowl & 7)) << 3)];
            *(bf16x8*)(yp + (size_t)(rowA0 + rowl) * N + colB0 + s * 8) = v8;
        }
    } else {
        // f32 tile in two row-halves of 128 x 1024 B = 128 KiB each
        float* smf = (float*)SM;
        float* op = (float*)outv;
#pragma unroll
        for (int h = 0; h < 2; ++h) {
            if (wr == h) {
#pragma unroll
                for (int ni = 0; ni < 4; ++ni) {
                    const int col = wc * 64 + ni * 16 + lrow;
                    const float bv = bias[colB0 + col];
#pragma unroll
                    for (int mi = 0; mi < 8; ++mi) {
#pragma unroll
                        for (int j = 0; j < 4; ++j) {
                            const int rowl = mi * 16 + kg * 4 + j;   // 0..127
                            const float v = acc[mi][ni][j] + bv;
                            const int fidx = rowl * 256 +
                                ((((col >> 2) ^ (rowl & 7)) << 2) | (col & 3));
                            smf[fidx] = v;
                        }
                    }
                }
            }
            __syncthreads();
#pragma unroll
            for (int p = 0; p < 16; ++p) {
                const int idx = p * 512 + tid;
                const int rowl = idx >> 6, s = idx & 63;
                const f32x4 v4 = *(const f32x4*)&smf[rowl * 256 + ((s ^ (rowl & 7)) << 2)];
                const size_t g = (size_t)(rowA0 + h * 128 + rowl) * N + colB0 + s * 4;
                const float4 rv = *(const float4*)&resid[g];
                float4 o4;
                o4.x = rv.x + 0.5f * v4[0];
                o4.y = rv.y + 0.5f * v4[1];
                o4.z = rv.z + 0.5f * v4[2];
                o4.w = rv.w + 0.5f * v4[3];
                *(float4*)&op[g] = o4;
            }
            __syncthreads();
        }
    }
}

extern "C" void kernel_launch(void* const* d_in, const int* in_sizes, int n_in,
                              void* d_out, int out_size, void* d_ws, size_t ws_size,
                              hipStream_t stream)
{
    const float* x      = (const float*)d_in[0];
    const float* gamma  = (const float*)d_in[1];
    const float* beta   = (const float*)d_in[2];
    const int*   fc1_q  = (const int*)d_in[3];
    const float* fc1_s  = (const float*)d_in[4];
    const float* fc1_b  = (const float*)d_in[5];
    const int*   fc2_q  = (const int*)d_in[6];
    const float* fc2_s  = (const float*)d_in[7];
    const float* fc2_b  = (const float*)d_in[8];
    float* out = (float*)d_out;

    char* ws = (char*)d_ws;
    __hip_bfloat16* w1t = (__hip_bfloat16*)ws;                            // [F][H]
    __hip_bfloat16* w2t = (__hip_bfloat16*)(ws + (size_t)FF * HH * 2);    // [H][F]
    char* dyn = ws + (size_t)2 * FF * HH * 2;
    const size_t avail = ws_size - (size_t)2 * FF * HH * 2;

    int MC = (int)(avail / ((size_t)(HH + FF) * 2));
    MC = (MC / 256) * 256;
    if (MC > MTOT) MC = MTOT;
    if (MC < 256)  MC = 256;

    __hip_bfloat16* hf_c = (__hip_bfloat16*)dyn;
    __hip_bfloat16* y_c  = (__hip_bfloat16*)(dyn + (size_t)MC * HH * 2);

    dequant_t_kernel<<<dim3(FF / 32, HH / 32), dim3(32, 8), 0, stream>>>(
        fc1_q, fc1_s, w1t, HH, FF);
    dequant_t_kernel<<<dim3(HH / 32, FF / 32), dim3(32, 8), 0, stream>>>(
        fc2_q, fc2_s, w2t, FF, HH);

    for (int m0 = 0; m0 < MTOT; m0 += MC) {
        const int mc = (MTOT - m0 < MC) ? (MTOT - m0) : MC;
        ln_kernel<<<mc, 256, 0, stream>>>(x, gamma, beta, hf_c, m0);
        gemm256<0, HH><<<dim3((FF / 256) * (mc / 256)), 512, 0, stream>>>(
            hf_c, w1t, fc1_b, nullptr, (void*)y_c, FF, FF / 256);
        gemm256<1, FF><<<dim3((HH / 256) * (mc / 256)), 512, 0, stream>>>(
            y_c, w2t, fc2_b, x + (size_t)m0 * HH, (void*)(out + (size_t)m0 * HH),
            HH, HH / 256);
    }
}